// Round 7
// baseline (167.702 us; speedup 1.0000x reference)
//
#include <hip/hip_runtime.h>

typedef _Float16 h2 __attribute__((ext_vector_type(2)));

#define CSTR 7     // column stride in DWORDS: (7*ly+2h)&31 -> 16 distinct banks per group
#define COLH 14    // halves per column (z0 halo, z1..8 interior, z9 halo, 4 pad halves)

// ---- DPP wave-64 sum (VALU pipe, not LDS pipe): result valid in lane 63 ----
template <int CTRL>
__device__ __forceinline__ float dpp_stage(float v) {
    int x = __builtin_amdgcn_update_dpp(0, __float_as_int(v), CTRL, 0xf, 0xf, true);
    return v + __int_as_float(x);
}
__device__ __forceinline__ float wave_sum(float v) {
    v = dpp_stage<0x111>(v);  // row_shr:1
    v = dpp_stage<0x112>(v);  // row_shr:2
    v = dpp_stage<0x114>(v);  // row_shr:4
    v = dpp_stage<0x118>(v);  // row_shr:8
    v = dpp_stage<0x142>(v);  // row_bcast:15
    v = dpp_stage<0x143>(v);  // row_bcast:31
    return v;                 // lane 63 holds the full sum
}

#define RFL(x) __int_as_float(__builtin_amdgcn_readfirstlane(__float_as_int(x)))

__device__ __forceinline__ h2 mid2(h2 lo, h2 hi) {
    // (lo.y, hi.x) as one whole-register op: v_alignbit_b32
    int r = __builtin_amdgcn_alignbit(__builtin_bit_cast(int, hi),
                                      __builtin_bit_cast(int, lo), 16);
    return __builtin_bit_cast(h2, r);
}
__device__ __forceinline__ h2 pkrtz(float a, float b) {
    return __builtin_bit_cast(h2, __builtin_amdgcn_cvt_pkrtz(a, b));
}

// ---- 27 taps x 4 z as 54 named h2 SSA values (register-resident) ----
#define R27(M) M(0) M(1) M(2) M(3) M(4) M(5) M(6) M(7) M(8) M(9) M(10) M(11) \
    M(12) M(13) M(14) M(15) M(16) M(17) M(18) M(19) M(20) M(21) M(22) M(23)  \
    M(24) M(25) M(26)

#define LOADW(T)                                                               \
    float4 f##T = *(const float4*)(W + ((size_t)(T) << 18) + ofs);             \
    h2 w##T##p = pkrtz(f##T.x, f##T.y);                                        \
    h2 w##T##q = pkrtz(f##T.z, f##T.w);                                        \
    sw0 += f##T.x; sw1 += f##T.y; sw2 += f##T.z; sw3 += f##T.w;

// one window column at dword offset O: 3 LDS dword reads (compiler merges to
// ds_read2+ds_read), 2 alignbit, 6 v_pk_fma_f16 -> covers 4 z outputs.
#define COLN(BP, O, T0, T1, T2) {                                              \
    h2 d0 = BP[(O)], d1 = BP[(O) + 1], d2 = BP[(O) + 2];                       \
    h2 m0 = mid2(d0, d1), m1 = mid2(d1, d2);                                   \
    dd0 = __builtin_elementwise_fma(d0, w##T0##p, dd0);                        \
    dd1 = __builtin_elementwise_fma(d1, w##T0##q, dd1);                        \
    dd0 = __builtin_elementwise_fma(m0, w##T1##p, dd0);                        \
    dd1 = __builtin_elementwise_fma(m1, w##T1##q, dd1);                        \
    dd0 = __builtin_elementwise_fma(d1, w##T2##p, dd0);                        \
    dd1 = __builtin_elementwise_fma(d2, w##T2##q, dd1); }

#define SILU(U) ((U) * __builtin_amdgcn_rcpf(1.f + __expf(-(U))))

// one inner iteration: 9 columns (3x3 xy window), 4 z outputs, 1 batch/thread;
// ONE barrier; reduction = 2 DPP chains (vs 8 in the 2z layout).
#define ITERX(BP, DSTB, RED) {                                                 \
    h2 dd0 = { (_Float16)0.f, (_Float16)0.f };                                 \
    h2 dd1 = dd0;                                                              \
    COLN(BP, 0,    0,  1,  2)                                                  \
    COLN(BP, 7,    3,  4,  5)                                                  \
    COLN(BP, 14,   6,  7,  8)                                                  \
    COLN(BP, 70,   9, 10, 11)                                                  \
    COLN(BP, 77,  12, 13, 14)                                                  \
    COLN(BP, 84,  15, 16, 17)                                                  \
    COLN(BP, 140, 18, 19, 20)                                                  \
    COLN(BP, 147, 21, 22, 23)                                                  \
    COLN(BP, 154, 24, 25, 26)                                                  \
    float mean = (halo_s + Si) * inv_n;                                        \
    float istd = rsqrtf((halo_q + Qi) * inv_n - mean * mean + 1e-5f);          \
    float u0 = ((float)dd0.x - mean * sw0) * istd + bf.x;                      \
    float u1 = ((float)dd0.y - mean * sw1) * istd + bf.y;                      \
    float u2 = ((float)dd1.x - mean * sw2) * istd + bf.z;                      \
    float u3 = ((float)dd1.y - mean * sw3) * istd + bf.w;                      \
    c0 += rf.x * SILU(u0);                                                     \
    c1 += rf.y * SILU(u1);                                                     \
    c2 += rf.z * SILU(u2);                                                     \
    c3 += rf.w * SILU(u3);                                                     \
    DSTB[ipc] = (_Float16)c0;                                                  \
    *(h2*)&DSTB[ipc + 1] = pkrtz(c1, c2);                                      \
    DSTB[ipc + 3] = (_Float16)c3;                                              \
    float sp = wave_sum((c0 + c1) + (c2 + c3));                                \
    float qp = wave_sum((c0 * c0 + c1 * c1) + (c2 * c2 + c3 * c3));            \
    if (lane == 63) RED[bh][wv1] = make_float2(sp, qp);                        \
    __syncthreads();                                                           \
    Si = RFL(RED[bh][0].x + RED[bh][1].x);                                     \
    Qi = RFL(RED[bh][0].y + RED[bh][1].y); }

__global__ __launch_bounds__(256)
void gridnet_kernel(const float* __restrict__ W,
                    const float* __restrict__ Bias,
                    const float* __restrict__ Rs,
                    const float* __restrict__ X,
                    float* __restrict__ Y,
                    int n_batch)
{
    __shared__ __align__(16) _Float16 bufA0[100 * COLH];   // 2.8 KB each
    __shared__ __align__(16) _Float16 bufA1[100 * COLH];
    __shared__ __align__(16) _Float16 bufB0[100 * COLH];
    __shared__ __align__(16) _Float16 bufB1[100 * COLH];
    __shared__ float4 red4[2][4];       // [batch][wave]
    __shared__ float2 redP[2][2][2];    // [pingpong][batch][wave-in-batch]

    const int tid = threadIdx.x;
    // bits: [0]=h (z-half, 4 z each), [1:3]=ly, [4:6]=lx, [7]=bh (batch).
    // bh is bit7 -> each WAVE handles a single batch (waves 0,1 = A; 2,3 = B).
    const int h    = tid & 1;
    const int ly   = (tid >> 1) & 7;
    const int lx   = (tid >> 4) & 7;
    const int bh   = tid >> 7;
    const int wave = tid >> 6;
    const int lane = tid & 63;
    const int wv1  = wave & 1;

    // NO XCD swizzle (round 4: cuts FETCH 5x but costs 20% via lockstep).
    const int np    = n_batch >> 1;      // batch PAIRS per tile
    const int bid   = blockIdx.x;
    const int r     = bid / np;          // spatial block 0..511
    const int pb    = bid - r * np;
    const int batch2 = 2 * pb;           // this wg: batches batch2, batch2+1
    const int gm0 = (r >> 6) << 3;
    const int gn0 = ((r >> 3) & 7) << 3;
    const int gk0 = (r & 7) << 3;

    const float* xb = X + ((size_t)batch2 << 18);

    // -------- stage 10x10x10 (zero halo) for both batches; stats on rounded --
    float sA_all = 0.f, qA_all = 0.f, sA_int = 0.f, qA_int = 0.f;
    float sB_all = 0.f, qB_all = 0.f, sB_int = 0.f, qB_int = 0.f;
    for (int i = tid; i < 1000; i += 256) {
        int ix = i / 100;
        int rem = i - ix * 100;
        int iy = rem / 10;
        int iz = rem - iy * 10;
        int m = gm0 + ix - 1, n = gn0 + iy - 1, k = gk0 + iz - 1;
        float vA = 0.f, vB = 0.f;
        if ((unsigned)m < 64u && (unsigned)n < 64u && (unsigned)k < 64u) {
            const float* p = xb + (m << 12) + (n << 6) + k;
            vA = p[0];
            vB = p[1 << 18];
        }
        _Float16 hA = (_Float16)vA, hB = (_Float16)vB;
        int a = (ix * 10 + iy) * COLH + iz;
        bufA0[a] = hA; bufA1[a] = hA;    // frozen halo must exist in both buffers
        bufB0[a] = hB; bufB1[a] = hB;
        float fA = (float)hA, fB = (float)hB;
        sA_all += fA; qA_all += fA * fA;
        sB_all += fB; qB_all += fB * fB;
        bool interior = ((unsigned)(ix - 1) < 8u) & ((unsigned)(iy - 1) < 8u) &
                        ((unsigned)(iz - 1) < 8u);
        if (interior) { sA_int += fA; qA_int += fA * fA;
                        sB_int += fB; qB_int += fB * fB; }
    }

    // -------- per-thread params: 27 taps x 4 z as 54 named h2 registers -----
    const int gm = gm0 + lx, gn = gn0 + ly;
    const size_t ofs = ((size_t)gm << 12) + (gn << 6) + gk0 + 4 * h;
    float sw0 = 0.f, sw1 = 0.f, sw2 = 0.f, sw3 = 0.f;
    R27(LOADW)
    const float4 bf = *(const float4*)(Bias + ofs);
    const float4 rf = *(const float4*)(Rs + ofs);

    // -------- one-time reduction: total + interior -> frozen halo sums ------
    {
        float a0 = wave_sum(sA_all), a1 = wave_sum(qA_all);
        float a2 = wave_sum(sA_int), a3 = wave_sum(qA_int);
        float b0 = wave_sum(sB_all), b1 = wave_sum(qB_all);
        float b2 = wave_sum(sB_int), b3 = wave_sum(qB_int);
        if (lane == 63) {
            red4[0][wave] = make_float4(a0, a1, a2, a3);
            red4[1][wave] = make_float4(b0, b1, b2, b3);
        }
    }
    __syncthreads();

    float S_all = 0.f, Q_all = 0.f, Si = 0.f, Qi = 0.f;
    #pragma unroll
    for (int wv = 0; wv < 4; ++wv) {
        float4 t = red4[bh][wv];          // own batch only
        S_all += t.x; Q_all += t.y; Si += t.z; Qi += t.w;
    }
    const float halo_s = RFL(S_all - Si);
    const float halo_q = RFL(Q_all - Qi);
    Si = RFL(Si); Qi = RFL(Qi);

    // -------- loop-invariant geometry (own batch's buffers) -----------------
    _Float16* const my0 = bh ? bufB0 : bufA0;
    _Float16* const my1 = bh ? bufB1 : bufA1;
    const int bpD = (lx * 10 + ly) * CSTR + 2 * h;     // window-corner dword
    const h2* const bp0 = (const h2*)my0 + bpD;
    const h2* const bp1 = (const h2*)my1 + bpD;
    const int ipc = ((lx + 1) * 10 + (ly + 1)) * COLH + 4 * h + 1;
    float c0 = (float)my0[ipc],     c1 = (float)my0[ipc + 1];
    float c2 = (float)my0[ipc + 2], c3 = (float)my0[ipc + 3];

    const float inv_n = 1.0f / 1000.0f;

    // 8 iterations = 4 ping-pong pairs; one barrier per iteration
    #pragma unroll 1
    for (int it = 0; it < 4; ++it) {
        ITERX(bp0, my1, redP[0])
        ITERX(bp1, my0, redP[1])
    }

    float* yp = Y + ((size_t)(batch2 + bh) << 18) + ofs;
    *(float4*)yp = make_float4(c0, c1, c2, c3);
}

extern "C" void kernel_launch(void* const* d_in, const int* in_sizes, int n_in,
                              void* d_out, int out_size, void* d_ws, size_t ws_size,
                              hipStream_t stream) {
    const float* W = (const float*)d_in[0];   // (27,64,64,64)
    const float* B = (const float*)d_in[1];   // (64,64,64)
    const float* R = (const float*)d_in[2];   // (64,64,64)
    const float* X = (const float*)d_in[3];   // (16,64,64,64)
    float* Y = (float*)d_out;

    int n_batch = in_sizes[3] >> 18;          // 64^3 per sample (16, even)
    dim3 grid(512 * (n_batch >> 1)), block(256);
    hipLaunchKernelGGL(gridnet_kernel, grid, block, 0, stream, W, B, R, X, Y, n_batch);
}

// Round 8
// 155.089 us; speedup vs baseline: 1.0813x; 1.0813x over previous
//
#include <hip/hip_runtime.h>

typedef _Float16 h2 __attribute__((ext_vector_type(2)));

#define CSTR 7     // column stride in DWORDS (odd -> bank spread)
#define COLH 14    // halves per column (= 2*CSTR): z0 halo, z1..8, z9 halo, 4 pad

// ---- DPP wave-64 sum (VALU pipe): full sum lands in lane 63 ----
template <int CTRL>
__device__ __forceinline__ float dpp_stage(float v) {
    int x = __builtin_amdgcn_update_dpp(0, __float_as_int(v), CTRL, 0xf, 0xf, true);
    return v + __int_as_float(x);
}
__device__ __forceinline__ float wave_sum(float v) {
    v = dpp_stage<0x111>(v);  // row_shr:1
    v = dpp_stage<0x112>(v);  // row_shr:2
    v = dpp_stage<0x114>(v);  // row_shr:4
    v = dpp_stage<0x118>(v);  // row_shr:8
    v = dpp_stage<0x142>(v);  // row_bcast:15
    v = dpp_stage<0x143>(v);  // row_bcast:31
    return v;
}

#define RFL(x) __int_as_float(__builtin_amdgcn_readfirstlane(__float_as_int(x)))

__device__ __forceinline__ h2 mid2(h2 lo, h2 hi) {
    int r = __builtin_amdgcn_alignbit(__builtin_bit_cast(int, hi),
                                      __builtin_bit_cast(int, lo), 16);
    return __builtin_bit_cast(h2, r);
}
__device__ __forceinline__ h2 pkrtz(float a, float b) {
    return __builtin_bit_cast(h2, __builtin_amdgcn_cvt_pkrtz(a, b));
}

// ---- 27 taps x 4 z as 54 named h2 SSA values (register-resident, r7-proven;
// shared by BOTH batches of this thread's pair) ----
#define R27(M) M(0) M(1) M(2) M(3) M(4) M(5) M(6) M(7) M(8) M(9) M(10) M(11) \
    M(12) M(13) M(14) M(15) M(16) M(17) M(18) M(19) M(20) M(21) M(22) M(23)  \
    M(24) M(25) M(26)

#define LOADW(T)                                                               \
    float4 f##T = *(const float4*)(W + ((size_t)(T) << 18) + ofs);             \
    h2 w##T##p = pkrtz(f##T.x, f##T.y);                                        \
    h2 w##T##q = pkrtz(f##T.z, f##T.w);                                        \
    sw0 += f##T.x; sw1 += f##T.y; sw2 += f##T.z; sw3 += f##T.w;

// one window column at dword offset O for one batch's accumulators D0N/D1N:
// 3 LDS dword reads, 2 alignbit, 6 v_pk_fma_f16 -> 4 z outputs.
#define COLN(BP, O, T0, T1, T2, D0N, D1N) {                                    \
    h2 d0 = BP[(O)], d1 = BP[(O) + 1], d2 = BP[(O) + 2];                       \
    h2 m0 = mid2(d0, d1), m1 = mid2(d1, d2);                                   \
    D0N = __builtin_elementwise_fma(d0, w##T0##p, D0N);                        \
    D1N = __builtin_elementwise_fma(d1, w##T0##q, D1N);                        \
    D0N = __builtin_elementwise_fma(m0, w##T1##p, D0N);                        \
    D1N = __builtin_elementwise_fma(m1, w##T1##q, D1N);                        \
    D0N = __builtin_elementwise_fma(d1, w##T2##p, D0N);                        \
    D1N = __builtin_elementwise_fma(d2, w##T2##q, D1N); }

#define DOT27(BP, D0N, D1N)                                                    \
    COLN(BP, 0,    0,  1,  2, D0N, D1N)                                        \
    COLN(BP, 7,    3,  4,  5, D0N, D1N)                                        \
    COLN(BP, 14,   6,  7,  8, D0N, D1N)                                        \
    COLN(BP, 70,   9, 10, 11, D0N, D1N)                                        \
    COLN(BP, 77,  12, 13, 14, D0N, D1N)                                        \
    COLN(BP, 84,  15, 16, 17, D0N, D1N)                                        \
    COLN(BP, 140, 18, 19, 20, D0N, D1N)                                        \
    COLN(BP, 147, 21, 22, 23, D0N, D1N)                                        \
    COLN(BP, 154, 24, 25, 26, D0N, D1N)

#define SILU(U) ((U) * __builtin_amdgcn_rcpf(1.f + __expf(-(U))))

// norm + bias + silu + residual + LDS writeback for one batch's 4 outputs
#define EPI4(DD0, DD1, SI, QI, HS, HQ, C0, C1, C2, C3, DSTB) {                 \
    float mean = (HS + SI) * inv_n;                                            \
    float istd = rsqrtf((HQ + QI) * inv_n - mean * mean + 1e-5f);              \
    float u0 = ((float)DD0.x - mean * sw0) * istd + bf.x;                      \
    float u1 = ((float)DD0.y - mean * sw1) * istd + bf.y;                      \
    float u2 = ((float)DD1.x - mean * sw2) * istd + bf.z;                      \
    float u3 = ((float)DD1.y - mean * sw3) * istd + bf.w;                      \
    C0 += rf.x * SILU(u0);                                                     \
    C1 += rf.y * SILU(u1);                                                     \
    C2 += rf.z * SILU(u2);                                                     \
    C3 += rf.w * SILU(u3);                                                     \
    DSTB[ipc] = (_Float16)C0;                                                  \
    *(h2*)&DSTB[ipc + 1] = pkrtz(C1, C2);                                      \
    DSTB[ipc + 3] = (_Float16)C3;  }

// one inner iteration for the thread's TWO batches: two independent
// dot/epilogue/DPP chains interleave (ILP, r5-proven); ONE barrier.
#define ITERP(BPA, DSTA, BPB, DSTB, RED) {                                     \
    h2 ddA0 = { (_Float16)0.f, (_Float16)0.f };                                \
    h2 ddA1 = ddA0, ddB0 = ddA0, ddB1 = ddA0;                                  \
    DOT27(BPA, ddA0, ddA1)                                                     \
    DOT27(BPB, ddB0, ddB1)                                                     \
    EPI4(ddA0, ddA1, SiA, QiA, halo_sA, halo_qA, cA0, cA1, cA2, cA3, DSTA)     \
    EPI4(ddB0, ddB1, SiB, QiB, halo_sB, halo_qB, cB0, cB1, cB2, cB3, DSTB)     \
    float spA = wave_sum((cA0 + cA1) + (cA2 + cA3));                           \
    float qpA = wave_sum((cA0 * cA0 + cA1 * cA1) + (cA2 * cA2 + cA3 * cA3));   \
    float spB = wave_sum((cB0 + cB1) + (cB2 + cB3));                           \
    float qpB = wave_sum((cB0 * cB0 + cB1 * cB1) + (cB2 * cB2 + cB3 * cB3));   \
    if (lane == 63) { RED[pg][0][wv1] = make_float2(spA, qpA);                 \
                      RED[pg][1][wv1] = make_float2(spB, qpB); }               \
    __syncthreads();                                                           \
    SiA = RFL(RED[pg][0][0].x + RED[pg][0][1].x);                              \
    QiA = RFL(RED[pg][0][0].y + RED[pg][0][1].y);                              \
    SiB = RFL(RED[pg][1][0].x + RED[pg][1][1].x);                              \
    QiB = RFL(RED[pg][1][0].y + RED[pg][1][1].y); }

__global__ __launch_bounds__(256)
void gridnet_kernel(const float* __restrict__ W,
                    const float* __restrict__ Bias,
                    const float* __restrict__ Rs,
                    const float* __restrict__ X,
                    float* __restrict__ Y,
                    int n_batch)
{
    // 4 batches/wg: [batch][pingpong], 2.8 KB each = 22.4 KB
    __shared__ __align__(16) _Float16 buf[4][2][100 * COLH];
    __shared__ float4 red4[4][4];          // [batch][wave] one-time stats
    __shared__ float2 redP[2][2][2][2];    // [pingpong][pg][batch01][wv1]

    const int tid = threadIdx.x;
    // bits: [0]=h (4 z each), [1:3]=ly, [4:6]=lx, [7]=pg (batch-pair group).
    const int h    = tid & 1;
    const int ly   = (tid >> 1) & 7;
    const int lx   = (tid >> 4) & 7;
    const int pg   = tid >> 7;             // waves 0,1 -> batches 0,1; 2,3 -> 2,3
    const int wave = tid >> 6;
    const int lane = tid & 63;
    const int wv1  = wave & 1;

    // NO XCD swizzle (round 4: cuts FETCH 5x but costs 20% via lockstep).
    const int np    = n_batch >> 2;        // batch QUADS per tile
    const int bid   = blockIdx.x;
    const int r     = bid / np;            // spatial block 0..511
    const int qb    = bid - r * np;
    const int batch0 = 4 * qb;             // this wg: batches batch0..batch0+3
    const int gm0 = (r >> 6) << 3;
    const int gn0 = ((r >> 3) & 7) << 3;
    const int gk0 = (r & 7) << 3;

    const float* xb = X + ((size_t)batch0 << 18);

    // -------- stage 10x10x10 (zero halo) for 4 batches; stats on rounded ----
    float sA_all = 0.f, qA_all = 0.f, sA_int = 0.f, qA_int = 0.f;
    float sB_all = 0.f, qB_all = 0.f, sB_int = 0.f, qB_int = 0.f;
    float sC_all = 0.f, qC_all = 0.f, sC_int = 0.f, qC_int = 0.f;
    float sD_all = 0.f, qD_all = 0.f, sD_int = 0.f, qD_int = 0.f;
    for (int i = tid; i < 1000; i += 256) {
        int ix = i / 100;
        int rem = i - ix * 100;
        int iy = rem / 10;
        int iz = rem - iy * 10;
        int m = gm0 + ix - 1, n = gn0 + iy - 1, k = gk0 + iz - 1;
        float vA = 0.f, vB = 0.f, vC = 0.f, vD = 0.f;
        if ((unsigned)m < 64u && (unsigned)n < 64u && (unsigned)k < 64u) {
            const float* p = xb + (m << 12) + (n << 6) + k;
            vA = p[0];
            vB = p[1 << 18];
            vC = p[2 << 18];
            vD = p[3 << 18];
        }
        _Float16 hA = (_Float16)vA, hB = (_Float16)vB;
        _Float16 hC = (_Float16)vC, hD = (_Float16)vD;
        int a = (ix * 10 + iy) * COLH + iz;
        buf[0][0][a] = hA; buf[0][1][a] = hA;   // frozen halo in both pingpongs
        buf[1][0][a] = hB; buf[1][1][a] = hB;
        buf[2][0][a] = hC; buf[2][1][a] = hC;
        buf[3][0][a] = hD; buf[3][1][a] = hD;
        float fA = (float)hA, fB = (float)hB, fC = (float)hC, fD = (float)hD;
        sA_all += fA; qA_all += fA * fA;
        sB_all += fB; qB_all += fB * fB;
        sC_all += fC; qC_all += fC * fC;
        sD_all += fD; qD_all += fD * fD;
        bool interior = ((unsigned)(ix - 1) < 8u) & ((unsigned)(iy - 1) < 8u) &
                        ((unsigned)(iz - 1) < 8u);
        if (interior) { sA_int += fA; qA_int += fA * fA;
                        sB_int += fB; qB_int += fB * fB;
                        sC_int += fC; qC_int += fC * fC;
                        sD_int += fD; qD_int += fD * fD; }
    }

    // one-time reduction for all 4 batches (16 independent DPP chains)
    {
        float a0 = wave_sum(sA_all), a1 = wave_sum(qA_all);
        float a2 = wave_sum(sA_int), a3 = wave_sum(qA_int);
        float b0 = wave_sum(sB_all), b1 = wave_sum(qB_all);
        float b2 = wave_sum(sB_int), b3 = wave_sum(qB_int);
        float c0 = wave_sum(sC_all), c1 = wave_sum(qC_all);
        float c2 = wave_sum(sC_int), c3 = wave_sum(qC_int);
        float d0 = wave_sum(sD_all), d1 = wave_sum(qD_all);
        float d2 = wave_sum(sD_int), d3 = wave_sum(qD_int);
        if (lane == 63) {
            red4[0][wave] = make_float4(a0, a1, a2, a3);
            red4[1][wave] = make_float4(b0, b1, b2, b3);
            red4[2][wave] = make_float4(c0, c1, c2, c3);
            red4[3][wave] = make_float4(d0, d1, d2, d3);
        }
    }

    // -------- per-thread params: 27 taps x 4 z as 54 named h2 registers -----
    const int gm = gm0 + lx, gn = gn0 + ly;
    const size_t ofs = ((size_t)gm << 12) + (gn << 6) + gk0 + 4 * h;
    float sw0 = 0.f, sw1 = 0.f, sw2 = 0.f, sw3 = 0.f;
    R27(LOADW)
    const float4 bf = *(const float4*)(Bias + ofs);
    const float4 rf = *(const float4*)(Rs + ofs);

    __syncthreads();   // staging + red4 visible

    // gather own pair's stats (batches 2pg, 2pg+1)
    float SA = 0.f, QA = 0.f, SiA = 0.f, QiA = 0.f;
    float SB = 0.f, QB = 0.f, SiB = 0.f, QiB = 0.f;
    #pragma unroll
    for (int wv = 0; wv < 4; ++wv) {
        float4 tA = red4[2 * pg][wv];
        float4 tB = red4[2 * pg + 1][wv];
        SA += tA.x; QA += tA.y; SiA += tA.z; QiA += tA.w;
        SB += tB.x; QB += tB.y; SiB += tB.z; QiB += tB.w;
    }
    const float halo_sA = RFL(SA - SiA), halo_qA = RFL(QA - QiA);
    const float halo_sB = RFL(SB - SiB), halo_qB = RFL(QB - QiB);
    SiA = RFL(SiA); QiA = RFL(QiA);
    SiB = RFL(SiB); QiB = RFL(QiB);

    // -------- loop-invariant geometry (own pair's buffers) ------------------
    const int bpD = (lx * 10 + ly) * CSTR + 2 * h;     // window-corner dword
    const h2* const bpA0 = (const h2*)buf[2 * pg][0] + bpD;
    const h2* const bpA1 = (const h2*)buf[2 * pg][1] + bpD;
    const h2* const bpB0 = (const h2*)buf[2 * pg + 1][0] + bpD;
    const h2* const bpB1 = (const h2*)buf[2 * pg + 1][1] + bpD;
    _Float16* const wrA0 = buf[2 * pg][0];
    _Float16* const wrA1 = buf[2 * pg][1];
    _Float16* const wrB0 = buf[2 * pg + 1][0];
    _Float16* const wrB1 = buf[2 * pg + 1][1];
    const int ipc = ((lx + 1) * 10 + (ly + 1)) * COLH + 4 * h + 1;
    float cA0 = (float)wrA0[ipc],     cA1 = (float)wrA0[ipc + 1];
    float cA2 = (float)wrA0[ipc + 2], cA3 = (float)wrA0[ipc + 3];
    float cB0 = (float)wrB0[ipc],     cB1 = (float)wrB0[ipc + 1];
    float cB2 = (float)wrB0[ipc + 2], cB3 = (float)wrB0[ipc + 3];

    const float inv_n = 1.0f / 1000.0f;

    // 8 iterations = 4 ping-pong pairs; one barrier per iteration
    #pragma unroll 1
    for (int it = 0; it < 4; ++it) {
        ITERP(bpA0, wrA1, bpB0, wrB1, redP[0])
        ITERP(bpA1, wrA0, bpB1, wrB0, redP[1])
    }

    float* yp = Y + ((size_t)(batch0 + 2 * pg) << 18) + ofs;
    *(float4*)yp = make_float4(cA0, cA1, cA2, cA3);
    *(float4*)(yp + (1 << 18)) = make_float4(cB0, cB1, cB2, cB3);
}

extern "C" void kernel_launch(void* const* d_in, const int* in_sizes, int n_in,
                              void* d_out, int out_size, void* d_ws, size_t ws_size,
                              hipStream_t stream) {
    const float* W = (const float*)d_in[0];   // (27,64,64,64)
    const float* B = (const float*)d_in[1];   // (64,64,64)
    const float* R = (const float*)d_in[2];   // (64,64,64)
    const float* X = (const float*)d_in[3];   // (16,64,64,64)
    float* Y = (float*)d_out;

    int n_batch = in_sizes[3] >> 18;          // 64^3 per sample (16, div by 4)
    dim3 grid(512 * (n_batch >> 2)), block(256);
    hipLaunchKernelGGL(gridnet_kernel, grid, block, 0, stream, W, B, R, X, Y, n_batch);
}

// Round 9
// 153.283 us; speedup vs baseline: 1.0941x; 1.0118x over previous
//
#include <hip/hip_runtime.h>

typedef _Float16 h2 __attribute__((ext_vector_type(2)));

#define CSTR 7     // column stride in DWORDS (odd -> bank spread)
#define COLH 14    // halves per column (= 2*CSTR): z0 halo, z1..8, z9 halo, 4 pad

// ---- DPP wave-64 sum (VALU pipe): full sum lands in lane 63 ----
template <int CTRL>
__device__ __forceinline__ float dpp_stage(float v) {
    int x = __builtin_amdgcn_update_dpp(0, __float_as_int(v), CTRL, 0xf, 0xf, true);
    return v + __int_as_float(x);
}
__device__ __forceinline__ float wave_sum(float v) {
    v = dpp_stage<0x111>(v);  // row_shr:1
    v = dpp_stage<0x112>(v);  // row_shr:2
    v = dpp_stage<0x114>(v);  // row_shr:4
    v = dpp_stage<0x118>(v);  // row_shr:8
    v = dpp_stage<0x142>(v);  // row_bcast:15
    v = dpp_stage<0x143>(v);  // row_bcast:31
    return v;
}

#define RFL(x) __int_as_float(__builtin_amdgcn_readfirstlane(__float_as_int(x)))

__device__ __forceinline__ h2 mid2(h2 lo, h2 hi) {
    int r = __builtin_amdgcn_alignbit(__builtin_bit_cast(int, hi),
                                      __builtin_bit_cast(int, lo), 16);
    return __builtin_bit_cast(h2, r);
}
__device__ __forceinline__ h2 pkrtz(float a, float b) {
    return __builtin_bit_cast(h2, __builtin_amdgcn_cvt_pkrtz(a, b));
}

// ---- 27 taps x 4 z as 54 named h2 SSA values (register-resident, r7/r8-proven;
// shared by BOTH batches of this thread's pair) ----
#define R27(M) M(0) M(1) M(2) M(3) M(4) M(5) M(6) M(7) M(8) M(9) M(10) M(11) \
    M(12) M(13) M(14) M(15) M(16) M(17) M(18) M(19) M(20) M(21) M(22) M(23)  \
    M(24) M(25) M(26)

#define LOADW(T)                                                               \
    float4 f##T = *(const float4*)(W + ((size_t)(T) << 18) + ofs);             \
    h2 w##T##p = pkrtz(f##T.x, f##T.y);                                        \
    h2 w##T##q = pkrtz(f##T.z, f##T.w);                                        \
    sw0 += f##T.x; sw1 += f##T.y; sw2 += f##T.z; sw3 += f##T.w;

// one window column at dword offset O for one batch's accumulators D0N/D1N:
// 3 LDS dword reads, 2 alignbit, 6 v_pk_fma_f16 -> 4 z outputs.
#define COLN(BP, O, T0, T1, T2, D0N, D1N) {                                    \
    h2 d0 = BP[(O)], d1 = BP[(O) + 1], d2 = BP[(O) + 2];                       \
    h2 m0 = mid2(d0, d1), m1 = mid2(d1, d2);                                   \
    D0N = __builtin_elementwise_fma(d0, w##T0##p, D0N);                        \
    D1N = __builtin_elementwise_fma(d1, w##T0##q, D1N);                        \
    D0N = __builtin_elementwise_fma(m0, w##T1##p, D0N);                        \
    D1N = __builtin_elementwise_fma(m1, w##T1##q, D1N);                        \
    D0N = __builtin_elementwise_fma(d1, w##T2##p, D0N);                        \
    D1N = __builtin_elementwise_fma(d2, w##T2##q, D1N); }

#define DOT27(BP, D0N, D1N)                                                    \
    COLN(BP, 0,    0,  1,  2, D0N, D1N)                                        \
    COLN(BP, 7,    3,  4,  5, D0N, D1N)                                        \
    COLN(BP, 14,   6,  7,  8, D0N, D1N)                                        \
    COLN(BP, 70,   9, 10, 11, D0N, D1N)                                        \
    COLN(BP, 77,  12, 13, 14, D0N, D1N)                                        \
    COLN(BP, 84,  15, 16, 17, D0N, D1N)                                        \
    COLN(BP, 140, 18, 19, 20, D0N, D1N)                                        \
    COLN(BP, 147, 21, 22, 23, D0N, D1N)                                        \
    COLN(BP, 154, 24, 25, 26, D0N, D1N)

#define SILU(U) ((U) * __builtin_amdgcn_rcpf(1.f + __expf(-(U))))

// norm + bias + silu + residual + LDS writeback for one batch's 4 outputs
#define EPI4(DD0, DD1, SI, QI, HS, HQ, C0, C1, C2, C3, DSTB) {                 \
    float mean = (HS + SI) * inv_n;                                            \
    float istd = rsqrtf((HQ + QI) * inv_n - mean * mean + 1e-5f);              \
    float u0 = ((float)DD0.x - mean * sw0) * istd + bf.x;                      \
    float u1 = ((float)DD0.y - mean * sw1) * istd + bf.y;                      \
    float u2 = ((float)DD1.x - mean * sw2) * istd + bf.z;                      \
    float u3 = ((float)DD1.y - mean * sw3) * istd + bf.w;                      \
    C0 += rf.x * SILU(u0);                                                     \
    C1 += rf.y * SILU(u1);                                                     \
    C2 += rf.z * SILU(u2);                                                     \
    C3 += rf.w * SILU(u3);                                                     \
    DSTB[ipc] = (_Float16)C0;                                                  \
    *(h2*)&DSTB[ipc + 1] = pkrtz(C1, C2);                                      \
    DSTB[ipc + 3] = (_Float16)C3;  }

// one inner iteration for the thread's TWO batches (A,B): two independent
// dot/epilogue/DPP chains interleave (ILP); ONE 2-wave barrier.
#define ITERP(BPA, DSTA, BPB, DSTB, RED) {                                     \
    h2 ddA0 = { (_Float16)0.f, (_Float16)0.f };                                \
    h2 ddA1 = ddA0, ddB0 = ddA0, ddB1 = ddA0;                                  \
    DOT27(BPA, ddA0, ddA1)                                                     \
    DOT27(BPB, ddB0, ddB1)                                                     \
    EPI4(ddA0, ddA1, SiA, QiA, halo_sA, halo_qA, cA0, cA1, cA2, cA3, DSTA)     \
    EPI4(ddB0, ddB1, SiB, QiB, halo_sB, halo_qB, cB0, cB1, cB2, cB3, DSTB)     \
    float spA = wave_sum((cA0 + cA1) + (cA2 + cA3));                           \
    float qpA = wave_sum((cA0 * cA0 + cA1 * cA1) + (cA2 * cA2 + cA3 * cA3));   \
    float spB = wave_sum((cB0 + cB1) + (cB2 + cB3));                           \
    float qpB = wave_sum((cB0 * cB0 + cB1 * cB1) + (cB2 * cB2 + cB3 * cB3));   \
    if (lane == 63) { RED[0][wave] = make_float2(spA, qpA);                    \
                      RED[1][wave] = make_float2(spB, qpB); }                  \
    __syncthreads();                                                           \
    SiA = RFL(RED[0][0].x + RED[0][1].x);                                      \
    QiA = RFL(RED[0][0].y + RED[0][1].y);                                      \
    SiB = RFL(RED[1][0].x + RED[1][1].x);                                      \
    QiB = RFL(RED[1][0].y + RED[1][1].y); }

__global__ __launch_bounds__(128)
void gridnet_kernel(const float* __restrict__ W,
                    const float* __restrict__ Bias,
                    const float* __restrict__ Rs,
                    const float* __restrict__ X,
                    float* __restrict__ Y,
                    int n_batch)
{
    // 2 batches/wg: [batch][pingpong], 2.8 KB each = 11.2 KB
    __shared__ __align__(16) _Float16 buf[2][2][100 * COLH];
    __shared__ float4 red4[2][2];          // [batch][wave] one-time stats
    __shared__ float2 redP[2][2][2];       // [pingpong][batch][wave]

    const int tid = threadIdx.x;           // 0..127, 2 waves
    // bits: [0]=h (4 z each), [1:3]=ly, [4:6]=lx
    const int h    = tid & 1;
    const int ly   = (tid >> 1) & 7;
    const int lx   = (tid >> 4) & 7;
    const int wave = tid >> 6;             // 0,1
    const int lane = tid & 63;

    // NO XCD swizzle (round 4: cuts FETCH 5x but costs 20% via lockstep).
    const int np    = n_batch >> 1;        // batch PAIRS per tile
    const int bid   = blockIdx.x;
    const int r     = bid / np;            // spatial block 0..511
    const int pb    = bid - r * np;
    const int batch0 = 2 * pb;             // this wg: batches batch0, batch0+1
    const int gm0 = (r >> 6) << 3;
    const int gn0 = ((r >> 3) & 7) << 3;
    const int gk0 = (r & 7) << 3;

    const float* xb = X + ((size_t)batch0 << 18);

    // -------- stage 10x10x10 (zero halo) for 2 batches; stats on rounded ----
    float sA_all = 0.f, qA_all = 0.f, sA_int = 0.f, qA_int = 0.f;
    float sB_all = 0.f, qB_all = 0.f, sB_int = 0.f, qB_int = 0.f;
    for (int i = tid; i < 1000; i += 128) {
        int ix = i / 100;
        int rem = i - ix * 100;
        int iy = rem / 10;
        int iz = rem - iy * 10;
        int m = gm0 + ix - 1, n = gn0 + iy - 1, k = gk0 + iz - 1;
        float vA = 0.f, vB = 0.f;
        if ((unsigned)m < 64u && (unsigned)n < 64u && (unsigned)k < 64u) {
            const float* p = xb + (m << 12) + (n << 6) + k;
            vA = p[0];
            vB = p[1 << 18];
        }
        _Float16 hA = (_Float16)vA, hB = (_Float16)vB;
        int a = (ix * 10 + iy) * COLH + iz;
        buf[0][0][a] = hA; buf[0][1][a] = hA;   // frozen halo in both pingpongs
        buf[1][0][a] = hB; buf[1][1][a] = hB;
        float fA = (float)hA, fB = (float)hB;
        sA_all += fA; qA_all += fA * fA;
        sB_all += fB; qB_all += fB * fB;
        bool interior = ((unsigned)(ix - 1) < 8u) & ((unsigned)(iy - 1) < 8u) &
                        ((unsigned)(iz - 1) < 8u);
        if (interior) { sA_int += fA; qA_int += fA * fA;
                        sB_int += fB; qB_int += fB * fB; }
    }

    // one-time reduction for both batches (8 independent DPP chains)
    {
        float a0 = wave_sum(sA_all), a1 = wave_sum(qA_all);
        float a2 = wave_sum(sA_int), a3 = wave_sum(qA_int);
        float b0 = wave_sum(sB_all), b1 = wave_sum(qB_all);
        float b2 = wave_sum(sB_int), b3 = wave_sum(qB_int);
        if (lane == 63) {
            red4[0][wave] = make_float4(a0, a1, a2, a3);
            red4[1][wave] = make_float4(b0, b1, b2, b3);
        }
    }

    // -------- per-thread params: 27 taps x 4 z as 54 named h2 registers -----
    const int gm = gm0 + lx, gn = gn0 + ly;
    const size_t ofs = ((size_t)gm << 12) + (gn << 6) + gk0 + 4 * h;
    float sw0 = 0.f, sw1 = 0.f, sw2 = 0.f, sw3 = 0.f;
    R27(LOADW)
    const float4 bf = *(const float4*)(Bias + ofs);
    const float4 rf = *(const float4*)(Rs + ofs);

    __syncthreads();   // staging + red4 visible (2 waves)

    // gather both batches' stats
    float SA = 0.f, QA = 0.f, SiA = 0.f, QiA = 0.f;
    float SB = 0.f, QB = 0.f, SiB = 0.f, QiB = 0.f;
    #pragma unroll
    for (int wv = 0; wv < 2; ++wv) {
        float4 tA = red4[0][wv];
        float4 tB = red4[1][wv];
        SA += tA.x; QA += tA.y; SiA += tA.z; QiA += tA.w;
        SB += tB.x; QB += tB.y; SiB += tB.z; QiB += tB.w;
    }
    const float halo_sA = RFL(SA - SiA), halo_qA = RFL(QA - QiA);
    const float halo_sB = RFL(SB - SiB), halo_qB = RFL(QB - QiB);
    SiA = RFL(SiA); QiA = RFL(QiA);
    SiB = RFL(SiB); QiB = RFL(QiB);

    // -------- loop-invariant geometry ---------------------------------------
    const int bpD = (lx * 10 + ly) * CSTR + 2 * h;     // window-corner dword
    const h2* const bpA0 = (const h2*)buf[0][0] + bpD;
    const h2* const bpA1 = (const h2*)buf[0][1] + bpD;
    const h2* const bpB0 = (const h2*)buf[1][0] + bpD;
    const h2* const bpB1 = (const h2*)buf[1][1] + bpD;
    _Float16* const wrA0 = buf[0][0];
    _Float16* const wrA1 = buf[0][1];
    _Float16* const wrB0 = buf[1][0];
    _Float16* const wrB1 = buf[1][1];
    const int ipc = ((lx + 1) * 10 + (ly + 1)) * COLH + 4 * h + 1;
    float cA0 = (float)wrA0[ipc],     cA1 = (float)wrA0[ipc + 1];
    float cA2 = (float)wrA0[ipc + 2], cA3 = (float)wrA0[ipc + 3];
    float cB0 = (float)wrB0[ipc],     cB1 = (float)wrB0[ipc + 1];
    float cB2 = (float)wrB0[ipc + 2], cB3 = (float)wrB0[ipc + 3];

    const float inv_n = 1.0f / 1000.0f;

    // 8 iterations = 4 ping-pong pairs; one 2-wave barrier per iteration
    #pragma unroll 1
    for (int it = 0; it < 4; ++it) {
        ITERP(bpA0, wrA1, bpB0, wrB1, redP[0])
        ITERP(bpA1, wrA0, bpB1, wrB0, redP[1])
    }

    float* yp = Y + ((size_t)batch0 << 18) + ofs;
    *(float4*)yp = make_float4(cA0, cA1, cA2, cA3);
    *(float4*)(yp + (1 << 18)) = make_float4(cB0, cB1, cB2, cB3);
}

extern "C" void kernel_launch(void* const* d_in, const int* in_sizes, int n_in,
                              void* d_out, int out_size, void* d_ws, size_t ws_size,
                              hipStream_t stream) {
    const float* W = (const float*)d_in[0];   // (27,64,64,64)
    const float* B = (const float*)d_in[1];   // (64,64,64)
    const float* R = (const float*)d_in[2];   // (64,64,64)
    const float* X = (const float*)d_in[3];   // (16,64,64,64)
    float* Y = (float*)d_out;

    int n_batch = in_sizes[3] >> 18;          // 64^3 per sample (16, even)
    dim3 grid(512 * (n_batch >> 1)), block(128);
    hipLaunchKernelGGL(gridnet_kernel, grid, block, 0, stream, W, B, R, X, Y, n_batch);
}